// Round 6
// baseline (201.369 us; speedup 1.0000x reference)
//
#include <hip/hip_runtime.h>
#include <hip/hip_bf16.h>

constexpr int Bn = 64, Sn = 512, Hn = 768, Tn = 9;
constexpr int EMS = 12;                  // padded emission row stride (floats)
constexpr int CHUNKS = 32, CLEN = 16;    // CHUNKS*CLEN == Sn
constexpr int WPAD = 776;                // padded Wt row stride

typedef __attribute__((ext_vector_type(8))) short bf16x8;
typedef __attribute__((ext_vector_type(4))) float f32x4;

__device__ __forceinline__ short f2bf(float x) {
    __hip_bfloat16 h = __float2bfloat16(x);
    return *reinterpret_cast<short*>(&h);
}

__device__ __forceinline__ float lse9(const float* e) {
    float m01 = fmaxf(e[0], e[1]), m23 = fmaxf(e[2], e[3]);
    float m45 = fmaxf(e[4], e[5]), m67 = fmaxf(e[6], e[7]);
    float m = fmaxf(fmaxf(fmaxf(m01, m23), fmaxf(m45, m67)), e[8]);
    float s = 0.f;
#pragma unroll
    for (int k = 0; k < 9; ++k) s += __expf(e[k] - m);
    return m + __logf(s);
}

// ---------------- K1: emissions via MFMA (bf16 in, f32 acc) ----------------
// One wave per 16-row tile. A-frags straight from global (no LDS, no shuffles);
// B (=W) built once into 24 register frags per lane. Same k-bijection
// sigma(hi,e)=hi*8+e used for A and B slots -> layout-permutation-proof.
__global__ __launch_bounds__(256, 2) void emis_kernel(
        const float* __restrict__ hidden, const float* __restrict__ W,
        const float* __restrict__ bias, float* __restrict__ em) {
    __shared__ float Wt[Tn * WPAD];      // W transposed: Wt[t][h]
    const int tid = threadIdx.x, lane = tid & 63;
    for (int f = tid; f < Hn * Tn; f += 256) {
        int h = f / 9, t = f - 9 * h;
        Wt[t * WPAD + h] = W[f];
    }
    __syncthreads();

    const int c16 = lane & 15, hi = lane >> 4;   // A-row / B-col index; k-group
    const bool on = c16 < Tn;
    bf16x8 bfrag[24];
#pragma unroll
    for (int m = 0; m < 24; ++m) {
        bf16x8 bf;
#pragma unroll
        for (int e = 0; e < 8; ++e) {
            float w = on ? Wt[c16 * WPAD + 32 * m + hi * 8 + e] : 0.f;
            bf[e] = f2bf(w);
        }
        bfrag[m] = bf;
    }
    const float bcol = on ? bias[c16] : 0.f;

    const int wid  = blockIdx.x * 4 + (tid >> 6);   // 0..2047, one tile each
    const int row0 = wid * 16;
    const float* abase = hidden + (size_t)(row0 + c16) * Hn + hi * 8;

    f32x4 acc = {0.f, 0.f, 0.f, 0.f};
#pragma unroll
    for (int m = 0; m < 24; ++m) {
        float4 u0 = *reinterpret_cast<const float4*>(abase + 32 * m);
        float4 u1 = *reinterpret_cast<const float4*>(abase + 32 * m + 4);
        bf16x8 af;
        af[0] = f2bf(u0.x); af[1] = f2bf(u0.y); af[2] = f2bf(u0.z); af[3] = f2bf(u0.w);
        af[4] = f2bf(u1.x); af[5] = f2bf(u1.y); af[6] = f2bf(u1.z); af[7] = f2bf(u1.w);
        acc = __builtin_amdgcn_mfma_f32_16x16x32_bf16(af, bfrag[m], acc, 0, 0, 0);
    }
    // D: row = hi*4 + i, col = c16 (m89-verified C/D mapping)
    if (on) {
        float* o = em + (size_t)(row0 + hi * 4) * EMS + c16;
#pragma unroll
        for (int i = 0; i < 4; ++i) o[(size_t)i * EMS] = acc[i] + bcol;
    }
}

// ---------------- K2: per-(batch,chunk) 9x9 log-matrix ----------------
__global__ __launch_bounds__(128) void chunk_kernel(
        const float* __restrict__ em, const float* __restrict__ trans,
        const int* __restrict__ labels, float* __restrict__ Mws) {
    const int b = blockIdx.x / CHUNKS;
    const int c = blockIdx.x % CHUNKS;
    const int tid = threadIdx.x;
    const bool act = tid < 81;
    const int i = tid / 9, j = tid % 9;
    __shared__ float Mbuf[2][9][12];
    __shared__ float emch[CLEN][EMS];
    __shared__ int   labch[CLEN];
    const int s0 = c * CLEN;
    const float* emb = em + ((size_t)b * Sn + s0) * EMS;
    for (int idx = tid; idx < CLEN * EMS; idx += 128)
        (&emch[0][0])[idx] = emb[idx];
    if (tid < CLEN) labch[tid] = labels[b * Sn + s0 + tid];
    float tc[9], row[9];
    float nv = (i == j) ? 0.f : -1e30f;
    if (act) {
#pragma unroll
        for (int k = 0; k < 9; ++k) tc[k] = trans[k * 9 + j];
#pragma unroll
        for (int k = 0; k < 9; ++k) row[k] = (k == i) ? 0.f : -1e30f;
    }
    __syncthreads();
    const int sbeg = (c == 0) ? 1 : 0;
    for (int sl = sbeg; sl < CLEN; ++sl) {
        if (act) {
            float e[9];
#pragma unroll
            for (int k = 0; k < 9; ++k) e[k] = row[k] + tc[k];
            float cand = lse9(e) + emch[sl][j];
            if (labch[sl] > -1) nv = cand;
            Mbuf[sl & 1][i][j] = nv;
        }
        __syncthreads();
        if (act) {
#pragma unroll
            for (int k = 0; k < 9; ++k) row[k] = Mbuf[sl & 1][i][k];
        }
    }
    if (act) Mws[(size_t)(b * CHUNKS + c) * 81 + tid] = nv;
}

// ---------------- K3: fold chunks + numerator + output ----------------
__global__ __launch_bounds__(128) void final_kernel(
        const float* __restrict__ em, const float* __restrict__ Mws,
        const float* __restrict__ start, const float* __restrict__ endt,
        const float* __restrict__ trans, const int* __restrict__ labels,
        float* __restrict__ out) {
    const int b = blockIdx.x, tid = threadIdx.x;
    __shared__ float Ml[CHUNKS][9][12];
    __shared__ float red[128];
    for (int idx = tid; idx < CHUNKS * 81; idx += 128) {
        int c = idx / 81, r = idx % 81;
        Ml[c][r / 9][r % 9] = Mws[(size_t)(b * CHUNKS + c) * 81 + r];
    }
    const int* lb = labels + b * Sn;
    float np = 0.f;
    for (int s = tid; s < Sn; s += 128) {
        if (s >= 1) {
            int l = lb[s];
            if (l > -1) {
                int tp = lb[s - 1]; tp = tp > -1 ? tp : 0;
                np += trans[tp * 9 + l] + em[((size_t)b * Sn + s) * EMS + l];
            }
        }
    }
    red[tid] = np;
    __syncthreads();
    for (int off = 64; off > 0; off >>= 1) {
        if (tid < off) red[tid] += red[tid + off];
        __syncthreads();
    }
    if (tid < 9) {
        const int j = tid;
        float alpha[9];
#pragma unroll
        for (int k = 0; k < 9; ++k)
            alpha[k] = start[k] + em[(size_t)b * Sn * EMS + k];
        for (int c = 0; c < CHUNKS; ++c) {
            float e[9];
#pragma unroll
            for (int k = 0; k < 9; ++k) e[k] = alpha[k] + Ml[c][k][j];
            float nv = lse9(e);
#pragma unroll
            for (int k = 0; k < 9; ++k) alpha[k] = __shfl(nv, k, 64);
        }
        if (j == 0) {
            float e[9];
#pragma unroll
            for (int k = 0; k < 9; ++k) e[k] = alpha[k] + endt[k];
            float den = lse9(e);
            int t0 = lb[0] > -1 ? lb[0] : 0;
            float num = red[0] + start[t0] + em[(size_t)b * Sn * EMS + t0];
            int lt = lb[Sn - 1] > -1 ? lb[Sn - 1] : 0;
            num += endt[lt];
            atomicAdd(out, (den - num) * (1.0f / Bn));
        }
    }
}

extern "C" void kernel_launch(void* const* d_in, const int* in_sizes, int n_in,
                              void* d_out, int out_size, void* d_ws, size_t ws_size,
                              hipStream_t stream) {
    const float* hidden = (const float*)d_in[0];
    const float* W      = (const float*)d_in[1];
    const float* bias   = (const float*)d_in[2];
    const float* start  = (const float*)d_in[3];
    const float* endt   = (const float*)d_in[4];
    const float* trans  = (const float*)d_in[5];
    const int*   labels = (const int*)d_in[6];
    float* out = (float*)d_out;

    float* em  = (float*)d_ws;                       // 32768*12 f32 = 1.5 MB
    float* Mws = em + (size_t)Bn * Sn * EMS;         // 64*32*81 f32

    hipMemsetAsync(d_out, 0, sizeof(float), stream);
    emis_kernel<<<512, 256, 0, stream>>>(hidden, W, bias, em);
    chunk_kernel<<<Bn * CHUNKS, 128, 0, stream>>>(em, trans, labels, Mws);
    final_kernel<<<Bn, 128, 0, stream>>>(em, Mws, start, endt, trans, labels, out);
}

// Round 8
// 199.574 us; speedup vs baseline: 1.0090x; 1.0090x over previous
//
#include <hip/hip_runtime.h>
#include <hip/hip_bf16.h>

constexpr int Bn = 64, Sn = 512, Hn = 768, Tn = 9;
constexpr int EMS = 12;                  // padded emission row stride (floats)
constexpr int CHUNKS = 32, CLEN = 16;    // CHUNKS*CLEN == Sn
constexpr int WPAD = 776;                // padded Wt row stride

typedef __attribute__((ext_vector_type(8))) short bf16x8;
typedef __attribute__((ext_vector_type(4))) float f32x4;

__device__ __forceinline__ short f2bf(float x) {
    __hip_bfloat16 h = __float2bfloat16(x);
    return *reinterpret_cast<short*>(&h);
}

__device__ __forceinline__ float lse9(const float* e) {
    float m01 = fmaxf(e[0], e[1]), m23 = fmaxf(e[2], e[3]);
    float m45 = fmaxf(e[4], e[5]), m67 = fmaxf(e[6], e[7]);
    float m = fmaxf(fmaxf(fmaxf(m01, m23), fmaxf(m45, m67)), e[8]);
    float s = 0.f;
#pragma unroll
    for (int k = 0; k < 9; ++k) s += __expf(e[k] - m);
    return m + __logf(s);
}

// ---- fused: one (b,chunk) block = 16 emission rows via ONE 16x16x(2x384) MFMA
//      tile (K split across 2 waves) + chunk 9x9 log-matrix + numerator ----
__global__ __launch_bounds__(128, 4) void fused_kernel(
        const float* __restrict__ hidden, const float* __restrict__ W,
        const float* __restrict__ bias, const float* __restrict__ trans,
        const int* __restrict__ labels,
        float* __restrict__ Mws, float* __restrict__ numpart,
        float* __restrict__ em0) {
    __shared__ float Wt[Tn * WPAD];       // 27936 B, W transposed Wt[t][h]
    __shared__ float emch[CLEN][EMS];     // emission tile
    __shared__ f32x4 acc1[64];            // wave1 partial accumulators
    __shared__ float Mbuf[2][9][12];
    __shared__ int   labch[CLEN + 1];     // [0]=label before chunk

    const int b = blockIdx.x / CHUNKS, c = blockIdx.x % CHUNKS;
    const int tid = threadIdx.x, lane = tid & 63, wv = tid >> 6;

    for (int f = tid; f < Hn * Tn; f += 128) {
        int h = f / 9, t = f - 9 * h;
        Wt[t * WPAD + h] = W[f];
    }
    if (tid < CLEN) labch[1 + tid] = labels[b * Sn + c * CLEN + tid];
    if (tid == CLEN) labch[0] = (c > 0) ? labels[b * Sn + c * CLEN - 1] : 0;
    __syncthreads();

    const int c16 = lane & 15, hi = lane >> 4;
    const bool on = c16 < Tn;

    // B-frags for this wave's K-range: k = wv*384 + 32*mm + hi*8 + e
    bf16x8 bfrag[12];
#pragma unroll
    for (int mm = 0; mm < 12; ++mm) {
        bf16x8 bf;
#pragma unroll
        for (int e = 0; e < 8; ++e) {
            float w = on ? Wt[c16 * WPAD + wv * 384 + 32 * mm + hi * 8 + e] : 0.f;
            bf[e] = f2bf(w);
        }
        bfrag[mm] = bf;
    }

    // A: rows b*Sn + c*16 + c16, this wave's K-range
    const float* abase = hidden + ((size_t)b * Sn + c * CLEN + c16) * Hn
                                + wv * 384 + hi * 8;
    f32x4 acc = {0.f, 0.f, 0.f, 0.f};
#pragma unroll
    for (int mm = 0; mm < 12; ++mm) {
        float4 u0 = *reinterpret_cast<const float4*>(abase + 32 * mm);
        float4 u1 = *reinterpret_cast<const float4*>(abase + 32 * mm + 4);
        bf16x8 af;
        af[0] = f2bf(u0.x); af[1] = f2bf(u0.y); af[2] = f2bf(u0.z); af[3] = f2bf(u0.w);
        af[4] = f2bf(u1.x); af[5] = f2bf(u1.y); af[6] = f2bf(u1.z); af[7] = f2bf(u1.w);
        acc = __builtin_amdgcn_mfma_f32_16x16x32_bf16(af, bfrag[mm], acc, 0, 0, 0);
    }
    if (wv == 1) acc1[lane] = acc;
    __syncthreads();
    if (wv == 0 && on) {
        f32x4 a1 = acc1[lane];
        const float bcol = bias[c16];
        // D mapping: row = hi*4 + i, col = c16 (m89-verified)
#pragma unroll
        for (int i = 0; i < 4; ++i) emch[hi * 4 + i][c16] = acc[i] + a1[i] + bcol;
    }
    __syncthreads();

    // ---- numerator partial for this chunk ----
    if (tid < 64) {
        float term = 0.f;
        if (tid < CLEN) {
            int sg = c * CLEN + tid;
            int l = labch[1 + tid];
            if (sg >= 1 && l > -1) {
                int lp = labch[tid]; if (lp < 0) lp = 0;
                term = trans[lp * 9 + l] + emch[tid][l];
            }
        }
#pragma unroll
        for (int m = 1; m < 16; m <<= 1) term += __shfl_xor(term, m, 64);
        if (tid == 0) numpart[b * CHUNKS + c] = term;
    }
    if (c == 0 && tid >= 64 && tid < 73) em0[b * EMS + (tid - 64)] = emch[0][tid - 64];

    // ---- chunk 9x9 log-semiring matrix ----
    const bool act = tid < 81;
    const int i = tid / 9, j = tid % 9;
    float tc[9], row[9];
    float nv = (i == j) ? 0.f : -1e30f;
    if (act) {
#pragma unroll
        for (int k = 0; k < 9; ++k) tc[k] = trans[k * 9 + j];
#pragma unroll
        for (int k = 0; k < 9; ++k) row[k] = (k == i) ? 0.f : -1e30f;
    }
    __syncthreads();
    const int sbeg = (c == 0) ? 1 : 0;
    for (int sl = sbeg; sl < CLEN; ++sl) {
        if (act) {
            float e[9];
#pragma unroll
            for (int k = 0; k < 9; ++k) e[k] = row[k] + tc[k];
            float cand = lse9(e) + emch[sl][j];
            if (labch[1 + sl] > -1) nv = cand;
            Mbuf[sl & 1][i][j] = nv;
        }
        __syncthreads();
        if (act) {
#pragma unroll
            for (int k = 0; k < 9; ++k) row[k] = Mbuf[sl & 1][i][k];
        }
    }
    if (act) Mws[(size_t)(b * CHUNKS + c) * 81 + tid] = nv;
}

// ---- final: fold 32 chunk matrices per batch + assemble loss ----
__global__ __launch_bounds__(128) void final_kernel(
        const float* __restrict__ Mws, const float* __restrict__ numpart,
        const float* __restrict__ em0, const float* __restrict__ start,
        const float* __restrict__ endt, const int* __restrict__ labels,
        float* __restrict__ out) {
    const int b = blockIdx.x, tid = threadIdx.x;
    __shared__ float Ml[CHUNKS][9][12];
    __shared__ float nred;
    for (int idx = tid; idx < CHUNKS * 81; idx += 128) {
        int c = idx / 81, r = idx % 81;
        Ml[c][r / 9][r % 9] = Mws[(size_t)(b * CHUNKS + c) * 81 + r];
    }
    if (tid < 64) {
        float np = (tid < CHUNKS) ? numpart[b * CHUNKS + tid] : 0.f;
#pragma unroll
        for (int m = 1; m < 32; m <<= 1) np += __shfl_xor(np, m, 64);
        if (tid == 0) nred = np;
    }
    __syncthreads();
    if (tid < 9) {
        const int j = tid;
        float alpha[9];
#pragma unroll
        for (int k = 0; k < 9; ++k) alpha[k] = start[k] + em0[b * EMS + k];
        for (int c = 0; c < CHUNKS; ++c) {
            float e[9];
#pragma unroll
            for (int k = 0; k < 9; ++k) e[k] = alpha[k] + Ml[c][k][j];
            float nv = lse9(e);
#pragma unroll
            for (int k = 0; k < 9; ++k) alpha[k] = __shfl(nv, k, 64);
        }
        if (j == 0) {
            float e[9];
#pragma unroll
            for (int k = 0; k < 9; ++k) e[k] = alpha[k] + endt[k];
            float den = lse9(e);
            const int* lb = labels + b * Sn;
            int t0 = lb[0] > -1 ? lb[0] : 0;
            int lt = lb[Sn - 1] > -1 ? lb[Sn - 1] : 0;
            float num = nred + start[t0] + em0[b * EMS + t0] + endt[lt];
            atomicAdd(out, (den - num) * (1.0f / Bn));
        }
    }
}

extern "C" void kernel_launch(void* const* d_in, const int* in_sizes, int n_in,
                              void* d_out, int out_size, void* d_ws, size_t ws_size,
                              hipStream_t stream) {
    const float* hidden = (const float*)d_in[0];
    const float* W      = (const float*)d_in[1];
    const float* bias   = (const float*)d_in[2];
    const float* start  = (const float*)d_in[3];
    const float* endt   = (const float*)d_in[4];
    const float* trans  = (const float*)d_in[5];
    const int*   labels = (const int*)d_in[6];
    float* out = (float*)d_out;

    float* numpart = (float*)d_ws;                    // 64*32
    float* em0     = numpart + Bn * CHUNKS;           // 64*12
    float* Mws     = em0 + Bn * EMS;                  // 64*32*81

    hipMemsetAsync(d_out, 0, sizeof(float), stream);
    fused_kernel<<<Bn * CHUNKS, 128, 0, stream>>>(hidden, W, bias, trans, labels,
                                                  Mws, numpart, em0);
    final_kernel<<<Bn, 128, 0, stream>>>(Mws, numpart, em0, start, endt, labels, out);
}

// Round 9
// 197.850 us; speedup vs baseline: 1.0178x; 1.0087x over previous
//
#include <hip/hip_runtime.h>
#include <hip/hip_bf16.h>

constexpr int Bn = 64, Sn = 512, Hn = 768, Tn = 9;
constexpr int EMS = 12;                  // padded emission row stride (floats)
constexpr int CHUNKS = 32, CLEN = 16;    // CHUNKS*CLEN == Sn
constexpr int ROWS = 64;                 // rows per emis block
constexpr int KC = 64;                   // K-chunk (floats)
constexpr int NKC = Hn / KC;             // 12

typedef __attribute__((ext_vector_type(8))) short bf16x8;
typedef __attribute__((ext_vector_type(4))) float f32x4;

__device__ __forceinline__ short f2bf(float x) {
    __hip_bfloat16 h = __float2bfloat16(x);
    return *reinterpret_cast<short*>(&h);
}

__device__ __forceinline__ void gl_lds16(const void* g, void* l) {
    __builtin_amdgcn_global_load_lds(
        (const __attribute__((address_space(1))) void*)g,
        (__attribute__((address_space(3))) void*)l, 16, 0, 0);
}

__device__ __forceinline__ float lse9(const float* e) {
    float m01 = fmaxf(e[0], e[1]), m23 = fmaxf(e[2], e[3]);
    float m45 = fmaxf(e[4], e[5]), m67 = fmaxf(e[6], e[7]);
    float m = fmaxf(fmaxf(fmaxf(m01, m23), fmaxf(m45, m67)), e[8]);
    float s = 0.f;
#pragma unroll
    for (int k = 0; k < 9; ++k) s += __expf(e[k] - m);
    return m + __logf(s);
}

// ---------------- K1: emissions, global_load_lds-staged MFMA ----------------
// 512 blocks x 4 waves; block owns 64 rows. A: 12 double-buffered K-chunks
// (64 rows x 64 f32 = 16KB) staged via 16B global_load_lds, source-side
// XOR-swizzle ((row&7) on 16B slots) -> conflict-free swizzled ds_reads.
// W: 24KB of bf16 MFMA B-frags built once per block. Wave w computes rows
// w*16..w*16+15 with 2 MFMAs per chunk, acc carried across chunks.
__global__ __launch_bounds__(256, 2) void emis_kernel(
        const float* __restrict__ hidden, const float* __restrict__ W,
        const float* __restrict__ bias, float* __restrict__ em) {
    __shared__ __align__(16) float Abuf[2][ROWS * KC];   // 2 x 16 KB
    __shared__ __align__(16) bf16x8 Wf[24 * 4 * 16];     // [mm][hi][c16], 24 KB

    const int tid = threadIdx.x, lane = tid & 63, wv = tid >> 6;
    const int R0 = blockIdx.x * ROWS;

    auto stage = [&](int kc, int bufi) {
#pragma unroll
        for (int gg = 0; gg < 4; ++gg) {
            const int g = wv * 4 + gg;              // 16 x 1KB per chunk
            const int row = 4 * g + (lane >> 4);
            const int cs = lane & 15;               // 16B slot in row
            const char* src = (const char*)(hidden + (size_t)(R0 + row) * Hn + kc * KC)
                              + ((cs ^ (row & 7)) << 4);
            gl_lds16(src, (char*)&Abuf[bufi][0] + (g << 10));
        }
    };

    stage(0, 0);  // issue first chunk before anything else

    // build W frags: entry n=(mm,hi,c16): e=0..7 -> bf16(W[(mm*32+hi*8+e)*9+c16])
    for (int n = tid; n < 24 * 4 * 16; n += 256) {
        const int mm = n >> 6, hj = (n >> 4) & 3, cc = n & 15;
        bf16x8 bf;
#pragma unroll
        for (int e = 0; e < 8; ++e) {
            float w = (cc < Tn) ? W[(mm * 32 + hj * 8 + e) * Tn + cc] : 0.f;
            bf[e] = f2bf(w);
        }
        Wf[n] = bf;
    }

    const int c16 = lane & 15, hi = lane >> 4;
    const bool on = c16 < Tn;
    const float bcol = on ? bias[c16] : 0.f;
    const int rloc = wv * 16 + c16;          // row within block tile
    const int swz = rloc & 7;

    __syncthreads();                         // chunk 0 + Wf ready

    f32x4 acc = {0.f, 0.f, 0.f, 0.f};
    for (int kc = 0; kc < NKC; ++kc) {
        if (kc + 1 < NKC) stage(kc + 1, (kc + 1) & 1);
        const char* Ab = (const char*)&Abuf[kc & 1][0] + rloc * KC * 4;
#pragma unroll
        for (int ml = 0; ml < 2; ++ml) {
            f32x4 a0 = *(const f32x4*)(Ab + (((ml * 8 + 2 * hi)     ^ swz) << 4));
            f32x4 a1 = *(const f32x4*)(Ab + (((ml * 8 + 2 * hi + 1) ^ swz) << 4));
            bf16x8 af;
            af[0] = f2bf(a0[0]); af[1] = f2bf(a0[1]);
            af[2] = f2bf(a0[2]); af[3] = f2bf(a0[3]);
            af[4] = f2bf(a1[0]); af[5] = f2bf(a1[1]);
            af[6] = f2bf(a1[2]); af[7] = f2bf(a1[3]);
            const int mmg = kc * 2 + ml;
            acc = __builtin_amdgcn_mfma_f32_16x16x32_bf16(
                af, Wf[(mmg * 4 + hi) * 16 + c16], acc, 0, 0, 0);
        }
        __syncthreads();                     // drains stage(kc+1) + read fence
    }

    // D mapping: row = hi*4 + i, col = c16 (m89-verified, validated r6/r8)
    if (on) {
#pragma unroll
        for (int i = 0; i < 4; ++i)
            em[(size_t)(R0 + wv * 16 + hi * 4 + i) * EMS + c16] = acc[i] + bcol;
    }
}

// ---------------- K2: per-(batch,chunk) 9x9 log-matrix ----------------
__global__ __launch_bounds__(128) void chunk_kernel(
        const float* __restrict__ em, const float* __restrict__ trans,
        const int* __restrict__ labels, float* __restrict__ Mws) {
    const int b = blockIdx.x / CHUNKS;
    const int c = blockIdx.x % CHUNKS;
    const int tid = threadIdx.x;
    const bool act = tid < 81;
    const int i = tid / 9, j = tid % 9;
    __shared__ float Mbuf[2][9][12];
    __shared__ float emch[CLEN][EMS];
    __shared__ int   labch[CLEN];
    const int s0 = c * CLEN;
    const float* emb = em + ((size_t)b * Sn + s0) * EMS;
    for (int idx = tid; idx < CLEN * EMS; idx += 128)
        (&emch[0][0])[idx] = emb[idx];
    if (tid < CLEN) labch[tid] = labels[b * Sn + s0 + tid];
    float tc[9], row[9];
    float nv = (i == j) ? 0.f : -1e30f;
    if (act) {
#pragma unroll
        for (int k = 0; k < 9; ++k) tc[k] = trans[k * 9 + j];
#pragma unroll
        for (int k = 0; k < 9; ++k) row[k] = (k == i) ? 0.f : -1e30f;
    }
    __syncthreads();
    const int sbeg = (c == 0) ? 1 : 0;
    for (int sl = sbeg; sl < CLEN; ++sl) {
        if (act) {
            float e[9];
#pragma unroll
            for (int k = 0; k < 9; ++k) e[k] = row[k] + tc[k];
            float cand = lse9(e) + emch[sl][j];
            if (labch[sl] > -1) nv = cand;
            Mbuf[sl & 1][i][j] = nv;
        }
        __syncthreads();
        if (act) {
#pragma unroll
            for (int k = 0; k < 9; ++k) row[k] = Mbuf[sl & 1][i][k];
        }
    }
    if (act) Mws[(size_t)(b * CHUNKS + c) * 81 + tid] = nv;
}

// ---------------- K3: fold chunks + numerator + output ----------------
__global__ __launch_bounds__(128) void final_kernel(
        const float* __restrict__ em, const float* __restrict__ Mws,
        const float* __restrict__ start, const float* __restrict__ endt,
        const float* __restrict__ trans, const int* __restrict__ labels,
        float* __restrict__ out) {
    const int b = blockIdx.x, tid = threadIdx.x;
    __shared__ float Ml[CHUNKS][9][12];
    __shared__ float red[128];
    for (int idx = tid; idx < CHUNKS * 81; idx += 128) {
        int c = idx / 81, r = idx % 81;
        Ml[c][r / 9][r % 9] = Mws[(size_t)(b * CHUNKS + c) * 81 + r];
    }
    const int* lb = labels + b * Sn;
    float np = 0.f;
    for (int s = tid; s < Sn; s += 128) {
        if (s >= 1) {
            int l = lb[s];
            if (l > -1) {
                int tp = lb[s - 1]; tp = tp > -1 ? tp : 0;
                np += trans[tp * 9 + l] + em[((size_t)b * Sn + s) * EMS + l];
            }
        }
    }
    red[tid] = np;
    __syncthreads();
    for (int off = 64; off > 0; off >>= 1) {
        if (tid < off) red[tid] += red[tid + off];
        __syncthreads();
    }
    if (tid < 9) {
        const int j = tid;
        float alpha[9];
#pragma unroll
        for (int k = 0; k < 9; ++k)
            alpha[k] = start[k] + em[(size_t)b * Sn * EMS + k];
        for (int c = 0; c < CHUNKS; ++c) {
            float e[9];
#pragma unroll
            for (int k = 0; k < 9; ++k) e[k] = alpha[k] + Ml[c][k][j];
            float nv = lse9(e);
#pragma unroll
            for (int k = 0; k < 9; ++k) alpha[k] = __shfl(nv, k, 64);
        }
        if (j == 0) {
            float e[9];
#pragma unroll
            for (int k = 0; k < 9; ++k) e[k] = alpha[k] + endt[k];
            float den = lse9(e);
            int t0 = lb[0] > -1 ? lb[0] : 0;
            float num = red[0] + start[t0] + em[(size_t)b * Sn * EMS + t0];
            int lt = lb[Sn - 1] > -1 ? lb[Sn - 1] : 0;
            num += endt[lt];
            atomicAdd(out, (den - num) * (1.0f / Bn));
        }
    }
}

extern "C" void kernel_launch(void* const* d_in, const int* in_sizes, int n_in,
                              void* d_out, int out_size, void* d_ws, size_t ws_size,
                              hipStream_t stream) {
    const float* hidden = (const float*)d_in[0];
    const float* W      = (const float*)d_in[1];
    const float* bias   = (const float*)d_in[2];
    const float* start  = (const float*)d_in[3];
    const float* endt   = (const float*)d_in[4];
    const float* trans  = (const float*)d_in[5];
    const int*   labels = (const int*)d_in[6];
    float* out = (float*)d_out;

    float* em  = (float*)d_ws;                       // 32768*12 f32 = 1.5 MB
    float* Mws = em + (size_t)Bn * Sn * EMS;         // 64*32*81 f32

    hipMemsetAsync(d_out, 0, sizeof(float), stream);
    emis_kernel<<<Bn * Sn / ROWS, 256, 0, stream>>>(hidden, W, bias, em);
    chunk_kernel<<<Bn * CHUNKS, 128, 0, stream>>>(em, trans, labels, Mws);
    final_kernel<<<Bn, 128, 0, stream>>>(em, Mws, start, endt, trans, labels, out);
}